// Round 1
// 235.687 us; speedup vs baseline: 1.3456x; 1.3456x over previous
//
#include <hip/hip_runtime.h>
#include <hip/hip_bf16.h>

typedef __hip_bfloat16 BF;
typedef __attribute__((ext_vector_type(8))) short bf16x8;
typedef __attribute__((ext_vector_type(4))) float f32x4;

// B=2, C=128, H=W=128, K=8, STRIDE=2, DIL=2, NH=8, dh=16, HID=170, Hc=Wc=64
// fp32 in / fp32 out. MFMA (bf16 inputs, fp32 acc) for the dense GEMMs.
// ws (floats): xt[0,4194304) kcb[+1048576) vcb[+1048576) ; packs (bf16) at 6291456:
//   packQ 16384, packK 16384, packV 16384, packP 16384, packF1 22528, packF2 24576

#define ASTR 200   // k_cell Abuf row stride in bf16: 400B -> 4-dword bank rotation (2-way, free)
#define KSTR 136   // k_kv Abuf row stride in bf16: 272B -> same rotation

__device__ __forceinline__ void gsum8(float v[8], float* red){
  #pragma unroll
  for(int s = 1; s < 64; s <<= 1){
    #pragma unroll
    for(int i = 0; i < 8; i++) v[i] += __shfl_xor(v[i], s);
  }
  const int wid = threadIdx.x >> 6;
  __syncthreads();
  if((threadIdx.x & 63) == 0){
    #pragma unroll
    for(int i = 0; i < 8; i++) red[wid*8 + i] = v[i];
  }
  __syncthreads();
  #pragma unroll
  for(int i = 0; i < 8; i++) v[i] = red[i] + red[8 + i];
}

// Row-stat reduction for C-layout accumulators: s1/s2 are per-reg partials over
// this lane's cols; result = totals over both waves' cols for row (lane>>4)*4+r.
__device__ __forceinline__ void rowred(float s1[4], float s2[4], float* red,
                                       int wave, int lane){
  #pragma unroll
  for(int m = 1; m < 16; m <<= 1){
    #pragma unroll
    for(int r = 0; r < 4; r++){ s1[r] += __shfl_xor(s1[r], m); s2[r] += __shfl_xor(s2[r], m); }
  }
  const int q4 = lane >> 4;
  __syncthreads();
  if((lane & 15) == 0){
    #pragma unroll
    for(int r = 0; r < 4; r++){
      red[wave*32 + q4*4 + r]      = s1[r];
      red[wave*32 + 16 + q4*4 + r] = s2[r];
    }
  }
  __syncthreads();
  #pragma unroll
  for(int r = 0; r < 4; r++){
    s1[r] = red[q4*4 + r]      + red[32 + q4*4 + r];
    s2[r] = red[16 + q4*4 + r] + red[48 + q4*4 + r];
  }
}

// ---- K0: tiled transpose x (B,C,H,W) -> xt (B,HW,C) ----
__global__ void k_tin(const float* __restrict__ x, float* __restrict__ xt){
  __shared__ float tile[32][33];
  const int b = blockIdx.z;
  const int pb = blockIdx.x * 32;
  const int cb = blockIdx.y * 32;
  const int tx = threadIdx.x, ty = threadIdx.y;
  #pragma unroll
  for(int r = 0; r < 32; r += 8)
    tile[ty+r][tx] = x[(size_t)(b*128 + cb+ty+r)*16384 + pb + tx];
  __syncthreads();
  #pragma unroll
  for(int r = 0; r < 32; r += 8)
    xt[(size_t)((b<<14) + pb + ty + r)*128 + cb + tx] = tile[tx][ty+r];
}

// ---- K1: pack weights to MFMA-B fragment layout, bf16 ----
__global__ void k_wt(const float* __restrict__ qkv_w, const float* __restrict__ proj_w,
                     const float* __restrict__ fc1_w, const float* __restrict__ fc2_w,
                     BF* __restrict__ pk){
  const int idx = blockIdx.x * 256 + threadIdx.x;
  if(idx >= 112640) return;
  float val;
  if(idx < 49152){                 // Q,K,V (N=128,S=4) from qkv_w[(reg*128+n)*128+k]
    const int reg = idx >> 14, l = idx & 16383;
    const int j = l & 7, q = (l>>3)&3, n = (l>>5)&127, s = l>>12;
    val = qkv_w[(reg*128 + n)*128 + (s*32 + q*8 + j)];
  } else if(idx < 65536){          // proj (N=128,S=4)
    const int l = idx - 49152;
    const int j = l&7, q=(l>>3)&3, n=(l>>5)&127, s=l>>12;
    val = proj_w[n*128 + (s*32+q*8+j)];
  } else if(idx < 88064){          // fc1 (N=176 pad, S=4)
    const int l = idx - 65536;
    const int j = l&7, q=(l>>3)&3, rem = l>>5;
    const int n = rem % 176, s = rem / 176;
    const int k = s*32+q*8+j;
    val = (n < 170) ? fc1_w[n*128 + k] : 0.f;
  } else {                         // fc2 (N=128, S=6, K pad 170->192)
    const int l = idx - 88064;
    const int j = l&7, q=(l>>3)&3, n=(l>>5)&127, s=l>>12;
    const int k = s*32+q*8+j;
    val = (k < 170) ? fc2_w[n*170 + k] : 0.f;
  }
  pk[idx] = __float2bfloat16(val);
}

// ---- K2: coarse k,v via MFMA: 8 coarse px/block ----
// Abuf rows 8..15 deliberately uninitialized: MFMA rows are independent and
// outputs for row>=8 are masked, so garbage there cannot reach valid outputs.
__global__ void __launch_bounds__(128)
k_kv(const float* __restrict__ xt,
     const BF* __restrict__ packK, const BF* __restrict__ packV,
     const float* __restrict__ qkv_b,
     const float* __restrict__ kg, const float* __restrict__ kb,
     const float* __restrict__ n1g, const float* __restrict__ n1b,
     float* __restrict__ kcb, float* __restrict__ vcb){
  __shared__ BF Abuf[16*KSTR];
  __shared__ float red[64];
  const int tid = threadIdx.x, wave = tid>>6, lane = tid&63;
  const int l15 = lane & 15, q4 = lane >> 4;
  const int bx = blockIdx.x;
  size_t prow[8];
  float xv[8];
  #pragma unroll
  for(int r = 0; r < 8; r++){
    const int cp = bx*8 + r;
    const int b = cp>>12, rm = cp&4095, ic = rm>>6, jcc = rm&63;
    prow[r] = ((size_t)(b*16384 + (2*ic)*128 + 2*jcc))*128;
    xv[r] = xt[prow[r] + tid];
  }
  float v[8];
  #pragma unroll
  for(int r = 0; r < 8; r++) v[r] = xv[r];
  gsum8(v, red);
  float xc[8], sq[8];
  #pragma unroll
  for(int r = 0; r < 8; r++){ xc[r] = xv[r] - v[r]*(1.f/128.f); sq[r] = xc[r]*xc[r]; }
  gsum8(sq, red);
  {
    const float g = n1g[tid], be = n1b[tid];
    #pragma unroll
    for(int r = 0; r < 8; r++)
      Abuf[r*KSTR + tid] = __float2bfloat16(xc[r]*rsqrtf(sq[r]*(1.f/128.f)+1e-6f)*g + be);
  }
  __syncthreads();
  bf16x8 af[4];
  #pragma unroll
  for(int s = 0; s < 4; s++) af[s] = *(const bf16x8*)&Abuf[l15*KSTR + s*32 + q4*8];

  // ---- k GEMM ----
  f32x4 acc[4];
  #pragma unroll
  for(int nt = 0; nt < 4; nt++){ acc[nt][0]=0.f; acc[nt][1]=0.f; acc[nt][2]=0.f; acc[nt][3]=0.f; }
  #pragma unroll
  for(int nt = 0; nt < 4; nt++){
    const int n = (wave*4+nt)*16 + l15;
    #pragma unroll
    for(int s = 0; s < 4; s++){
      bf16x8 bf = *(const bf16x8*)&packK[((s*128 + n)*4 + q4)*8];
      acc[nt] = __builtin_amdgcn_mfma_f32_16x16x32_bf16(af[s], bf, acc[nt], 0,0,0);
    }
  }
  float s1[4], s2[4], colb[4];
  #pragma unroll
  for(int r = 0; r < 4; r++){ s1[r]=0.f; s2[r]=0.f; }
  #pragma unroll
  for(int nt = 0; nt < 4; nt++){
    colb[nt] = qkv_b[128 + (wave*4+nt)*16 + l15];
    #pragma unroll
    for(int r = 0; r < 4; r++){
      const float vv = acc[nt][r] + colb[nt];
      acc[nt][r] = vv; s1[r] += vv; s2[r] += vv*vv;
    }
  }
  rowred(s1, s2, red, wave, lane);
  #pragma unroll
  for(int nt = 0; nt < 4; nt++){
    const int col = (wave*4+nt)*16 + l15;
    const float g = kg[col], be = kb[col];
    #pragma unroll
    for(int r = 0; r < 4; r++){
      const int row = q4*4 + r;
      if(row < 8){
        const float mu = s1[r]*(1.f/128.f);
        const float var = s2[r]*(1.f/128.f) - mu*mu;
        kcb[(size_t)(bx*8+row)*128 + col] = (acc[nt][r]-mu)*rsqrtf(var+1e-6f)*g + be;
      }
    }
  }
  // ---- v GEMM ----
  #pragma unroll
  for(int nt = 0; nt < 4; nt++){ acc[nt][0]=0.f; acc[nt][1]=0.f; acc[nt][2]=0.f; acc[nt][3]=0.f; }
  #pragma unroll
  for(int nt = 0; nt < 4; nt++){
    const int n = (wave*4+nt)*16 + l15;
    #pragma unroll
    for(int s = 0; s < 4; s++){
      bf16x8 bf = *(const bf16x8*)&packV[((s*128 + n)*4 + q4)*8];
      acc[nt] = __builtin_amdgcn_mfma_f32_16x16x32_bf16(af[s], bf, acc[nt], 0,0,0);
    }
  }
  #pragma unroll
  for(int nt = 0; nt < 4; nt++){
    const int col = (wave*4+nt)*16 + l15;
    const float bv = qkv_b[256 + col];
    #pragma unroll
    for(int r = 0; r < 4; r++){
      const int row = q4*4 + r;
      if(row < 8) vcb[(size_t)(bx*8+row)*128 + col] = acc[nt][r] + bv;
    }
  }
}

// ---- K3: fused per-2-cells (8 pixels) block, MFMA GEMMs ----
// LDS: Abuf (16*ASTR bf16 = 6400B) unioned with sc4 (512 float4 = 8192B):
// Abuf live LN1->qGEMM and ao->fc2; sc4 live only inside attention. Union + no
// zero-init drops LDS 23552 -> ~17.2KB => 9 blocks/CU instead of 6.
__global__ void __launch_bounds__(128, 4)
k_cell(const float* __restrict__ xt_in,
       const BF* __restrict__ packQ, const BF* __restrict__ packP,
       const BF* __restrict__ packF1, const BF* __restrict__ packF2,
       const float* __restrict__ qkv_b,
       const float* __restrict__ qg, const float* __restrict__ qb,
       const float* __restrict__ n1g, const float* __restrict__ n1b,
       const float* __restrict__ proj_b,
       const float* __restrict__ ls1, const float* __restrict__ ls2,
       const float* __restrict__ n2g, const float* __restrict__ n2b,
       const float* __restrict__ fc1_b,
       const float* __restrict__ mg, const float* __restrict__ mb,
       const float* __restrict__ fc2_b,
       const float* __restrict__ kcb, const float* __restrict__ vcb,
       float* __restrict__ xt_out){
  __shared__ float4 uni[512];          // 8192B union region
  BF* const Abuf = (BF*)uni;           // [16][ASTR] bf16
  float4* const sc4 = uni;             // [512] float4
  __shared__ float xvL[8*128];
  __shared__ float4 qnA[128], qnB[128];
  __shared__ int cidxA[64], cidxB[64]; // SAFE indices (0 when invalid)
  __shared__ float red[64];
  const int tid = threadIdx.x, wave = tid>>6, lane = tid&63;
  const int l15 = lane & 15, q4 = lane >> 4;

  const int bx = blockIdx.x;
  const int b = bx >> 11, rem = bx & 2047, ip = rem >> 6, jc = rem & 63;
  const int icA = 2*ip, icB = 2*ip + 1;
  const size_t p0 = (size_t)b*16384*128 + ((size_t)(4*ip)*128 + 2*jc)*128;
  float xv[8];
  #pragma unroll
  for(int r = 0; r < 8; r++){
    const size_t pr = p0 + ((size_t)(r>>1)<<14) + (size_t)((r&1)<<7);
    xv[r] = xt_in[pr + tid]; xvL[r*128 + tid] = xv[r];
  }

  // ---- LN1 ----
  float v[8];
  #pragma unroll
  for(int r = 0; r < 8; r++) v[r] = xv[r];
  gsum8(v, red);
  float xc[8], sq[8];
  #pragma unroll
  for(int r = 0; r < 8; r++){ xc[r] = xv[r] - v[r]*(1.f/128.f); sq[r] = xc[r]*xc[r]; }
  gsum8(sq, red);
  {
    const float g = n1g[tid], be = n1b[tid];
    #pragma unroll
    for(int r = 0; r < 8; r++)
      Abuf[r*ASTR + tid] = __float2bfloat16(xc[r]*rsqrtf(sq[r]*(1.f/128.f)+1e-6f)*g + be);
  }
  if(tid < 64){
    const int i = tid >> 3, j = tid & 7;
    const int rj = jc + 2*j - 8;
    const bool vj = (rj >= 0) && (rj < 64);
    const int riA = icA + 2*i - 8, riB = icB + 2*i - 8;
    cidxA[tid] = (vj && riA >= 0 && riA < 64) ? ((b*4096 + riA*64 + rj)*128) : 0;
    cidxB[tid] = (vj && riB >= 0 && riB < 64) ? ((b*4096 + riB*64 + rj)*128) : 0;
  }
  __syncthreads();

  // ---- q GEMM + q-LN -> qnA/qnB ----
  {
    bf16x8 af[4];
    #pragma unroll
    for(int s = 0; s < 4; s++) af[s] = *(const bf16x8*)&Abuf[l15*ASTR + s*32 + q4*8];
    f32x4 acc[4];
    #pragma unroll
    for(int nt = 0; nt < 4; nt++){ acc[nt][0]=0.f; acc[nt][1]=0.f; acc[nt][2]=0.f; acc[nt][3]=0.f; }
    #pragma unroll
    for(int nt = 0; nt < 4; nt++){
      const int n = (wave*4+nt)*16 + l15;
      #pragma unroll
      for(int s = 0; s < 4; s++){
        bf16x8 bf = *(const bf16x8*)&packQ[((s*128 + n)*4 + q4)*8];
        acc[nt] = __builtin_amdgcn_mfma_f32_16x16x32_bf16(af[s], bf, acc[nt], 0,0,0);
      }
    }
    float s1[4], s2[4];
    #pragma unroll
    for(int r = 0; r < 4; r++){ s1[r]=0.f; s2[r]=0.f; }
    #pragma unroll
    for(int nt = 0; nt < 4; nt++){
      const float cb2 = qkv_b[(wave*4+nt)*16 + l15];
      #pragma unroll
      for(int r = 0; r < 4; r++){
        const float vv = acc[nt][r] + cb2;
        acc[nt][r] = vv; s1[r] += vv; s2[r] += vv*vv;
      }
    }
    rowred(s1, s2, red, wave, lane);
    if(q4 < 2){
      float mu[4], rs[4];
      #pragma unroll
      for(int r = 0; r < 4; r++){
        mu[r] = s1[r]*(1.f/128.f);
        rs[r] = rsqrtf(s2[r]*(1.f/128.f) - mu[r]*mu[r] + 1e-6f);
      }
      #pragma unroll
      for(int nt = 0; nt < 4; nt++){
        const int col = (wave*4+nt)*16 + l15;
        const float g = qg[col], be = qb[col];
        float4 t;
        t.x = (acc[nt][0]-mu[0])*rs[0]*g + be;
        t.y = (acc[nt][1]-mu[1])*rs[1]*g + be;
        t.z = (acc[nt][2]-mu[2])*rs[2]*g + be;
        t.w = (acc[nt][3]-mu[3])*rs[3]*g + be;
        if(q4 == 0) qnA[col] = t; else qnB[col] = t;
      }
    }
  }
  __syncthreads();

  // ---- attention: branch-free, vectorized K loads, batched V loads ----
  // Masking: score = qk*0.25 + madd with madd in {0,-1e30}. exp(-1e30 - m)
  // underflows to exactly 0 (center neighbor always valid => m finite), so
  // invalid neighbors contribute exactly 0 in PV with the safe index.
  const int i8 = lane >> 3, j8 = lane & 7;
  const int rjm = jc + 2*j8 - 8;
  const bool vjm = (rjm >= 0) && (rjm < 64);
  const int riAm = icA + 2*i8 - 8, riBm = icB + 2*i8 - 8;
  const float maddA = (vjm && riAm >= 0 && riAm < 64) ? 0.f : -1e30f;
  const float maddB = (vjm && riBm >= 0 && riBm < 64) ? 0.f : -1e30f;

  float4 oA, oB;
  for(int cell = 0; cell < 2; cell++){
    const int* cidx = cell ? cidxB : cidxA;
    const float4* qn = cell ? qnB : qnA;
    const float madd = cell ? maddB : maddA;
    // QK: nb == lane for every rep; head n = rep*2 + wave.
    {
      const int ci = cidx[lane];
      float4 kf[4][4];
      #pragma unroll
      for(int rep = 0; rep < 4; rep++){
        const int n = rep*2 + wave;
        const float4* kp4 = (const float4*)(kcb + (size_t)ci + n*16);
        #pragma unroll
        for(int d4 = 0; d4 < 4; d4++) kf[rep][d4] = kp4[d4];
      }
      #pragma unroll
      for(int rep = 0; rep < 4; rep++){
        const int n = rep*2 + wave;
        float4 a; a.x = 0.f; a.y = 0.f; a.z = 0.f; a.w = 0.f;
        #pragma unroll
        for(int d4 = 0; d4 < 4; d4++){
          const float4 kv = kf[rep][d4];
          #pragma unroll
          for(int e = 0; e < 4; e++){
            const float4 qq = qn[n*16 + d4*4 + e];
            const float kd = (e==0) ? kv.x : (e==1) ? kv.y : (e==2) ? kv.z : kv.w;
            a.x += qq.x*kd; a.y += qq.y*kd; a.z += qq.z*kd; a.w += qq.w*kd;
          }
        }
        float4 s;
        s.x = a.x*0.25f + madd; s.y = a.y*0.25f + madd;
        s.z = a.z*0.25f + madd; s.w = a.w*0.25f + madd;
        sc4[rep*128 + tid] = s;
      }
    }
    __syncthreads();
    {
      const int n = tid >> 4, l = tid & 15;
      float4 s0 = sc4[n*64 + l], s1 = sc4[n*64 + l + 16];
      float4 s2 = sc4[n*64 + l + 32], s3 = sc4[n*64 + l + 48];
      float4 m;
      m.x = fmaxf(fmaxf(s0.x,s1.x), fmaxf(s2.x,s3.x));
      m.y = fmaxf(fmaxf(s0.y,s1.y), fmaxf(s2.y,s3.y));
      m.z = fmaxf(fmaxf(s0.z,s1.z), fmaxf(s2.z,s3.z));
      m.w = fmaxf(fmaxf(s0.w,s1.w), fmaxf(s2.w,s3.w));
      #pragma unroll
      for(int sft = 1; sft < 16; sft <<= 1){
        m.x = fmaxf(m.x, __shfl_xor(m.x, sft));
        m.y = fmaxf(m.y, __shfl_xor(m.y, sft));
        m.z = fmaxf(m.z, __shfl_xor(m.z, sft));
        m.w = fmaxf(m.w, __shfl_xor(m.w, sft));
      }
      float4 e0, e1, e2, e3, es;
      e0.x = __expf(s0.x-m.x); e0.y = __expf(s0.y-m.y); e0.z = __expf(s0.z-m.z); e0.w = __expf(s0.w-m.w);
      e1.x = __expf(s1.x-m.x); e1.y = __expf(s1.y-m.y); e1.z = __expf(s1.z-m.z); e1.w = __expf(s1.w-m.w);
      e2.x = __expf(s2.x-m.x); e2.y = __expf(s2.y-m.y); e2.z = __expf(s2.z-m.z); e2.w = __expf(s2.w-m.w);
      e3.x = __expf(s3.x-m.x); e3.y = __expf(s3.y-m.y); e3.z = __expf(s3.z-m.z); e3.w = __expf(s3.w-m.w);
      es.x = e0.x+e1.x+e2.x+e3.x; es.y = e0.y+e1.y+e2.y+e3.y;
      es.z = e0.z+e1.z+e2.z+e3.z; es.w = e0.w+e1.w+e2.w+e3.w;
      #pragma unroll
      for(int sft = 1; sft < 16; sft <<= 1){
        es.x += __shfl_xor(es.x, sft); es.y += __shfl_xor(es.y, sft);
        es.z += __shfl_xor(es.z, sft); es.w += __shfl_xor(es.w, sft);
      }
      float4 inv; inv.x = 1.f/es.x; inv.y = 1.f/es.y; inv.z = 1.f/es.z; inv.w = 1.f/es.w;
      float4 o;
      o.x = e0.x*inv.x; o.y = e0.y*inv.y; o.z = e0.z*inv.z; o.w = e0.w*inv.w; sc4[n*64+l]    = o;
      o.x = e1.x*inv.x; o.y = e1.y*inv.y; o.z = e1.z*inv.z; o.w = e1.w*inv.w; sc4[n*64+l+16] = o;
      o.x = e2.x*inv.x; o.y = e2.y*inv.y; o.z = e2.z*inv.z; o.w = e2.w*inv.w; sc4[n*64+l+32] = o;
      o.x = e3.x*inv.x; o.y = e3.y*inv.y; o.z = e3.z*inv.z; o.w = e3.w*inv.w; sc4[n*64+l+48] = o;
    }
    __syncthreads();
    {
      const int n = tid >> 4;
      float4 o; o.x = 0.f; o.y = 0.f; o.z = 0.f; o.w = 0.f;
      #pragma unroll 2
      for(int nb0 = 0; nb0 < 64; nb0 += 8){
        float vv[8];
        #pragma unroll
        for(int u = 0; u < 8; u++) vv[u] = vcb[(size_t)cidx[nb0+u] + tid];
        #pragma unroll
        for(int u = 0; u < 8; u++){
          const float4 pr = sc4[n*64 + nb0 + u];
          o.x += pr.x*vv[u]; o.y += pr.y*vv[u]; o.z += pr.z*vv[u]; o.w += pr.w*vv[u];
        }
      }
      if(cell == 0) oA = o; else oB = o;
    }
    __syncthreads();
  }
  // ao -> Abuf (A of proj)
  Abuf[0*ASTR + tid] = __float2bfloat16(oA.x);
  Abuf[1*ASTR + tid] = __float2bfloat16(oA.y);
  Abuf[2*ASTR + tid] = __float2bfloat16(oA.z);
  Abuf[3*ASTR + tid] = __float2bfloat16(oA.w);
  Abuf[4*ASTR + tid] = __float2bfloat16(oB.x);
  Abuf[5*ASTR + tid] = __float2bfloat16(oB.y);
  Abuf[6*ASTR + tid] = __float2bfloat16(oB.z);
  Abuf[7*ASTR + tid] = __float2bfloat16(oB.w);
  __syncthreads();

  // ---- proj GEMM + ls1*res -> xh (C-layout regs), LN2 -> Abuf ----
  float xh[4][4];
  {
    bf16x8 af[4];
    #pragma unroll
    for(int s = 0; s < 4; s++) af[s] = *(const bf16x8*)&Abuf[l15*ASTR + s*32 + q4*8];
    f32x4 acc[4];
    #pragma unroll
    for(int nt = 0; nt < 4; nt++){ acc[nt][0]=0.f; acc[nt][1]=0.f; acc[nt][2]=0.f; acc[nt][3]=0.f; }
    #pragma unroll
    for(int nt = 0; nt < 4; nt++){
      const int n = (wave*4+nt)*16 + l15;
      #pragma unroll
      for(int s = 0; s < 4; s++){
        bf16x8 bf = *(const bf16x8*)&packP[((s*128 + n)*4 + q4)*8];
        acc[nt] = __builtin_amdgcn_mfma_f32_16x16x32_bf16(af[s], bf, acc[nt], 0,0,0);
      }
    }
    float s1[4], s2[4];
    #pragma unroll
    for(int r = 0; r < 4; r++){ s1[r]=0.f; s2[r]=0.f; }
    #pragma unroll
    for(int nt = 0; nt < 4; nt++){
      const int col = (wave*4+nt)*16 + l15;
      const float bp = proj_b[col], l1 = ls1[col];
      #pragma unroll
      for(int r = 0; r < 4; r++){
        const int row = q4*4 + r;
        const float xvv = (row < 8) ? xvL[row*128 + col] : 0.f;
        const float hx = xvv + l1*(acc[nt][r] + bp);
        xh[nt][r] = hx; s1[r] += hx; s2[r] += hx*hx;
      }
    }
    rowred(s1, s2, red, wave, lane);
    #pragma unroll
    for(int nt = 0; nt < 4; nt++){
      const int col = (wave*4+nt)*16 + l15;
      const float g = n2g[col], be = n2b[col];
      #pragma unroll
      for(int r = 0; r < 4; r++){
        const int row = q4*4 + r;
        if(row < 8){
          const float mu = s1[r]*(1.f/128.f);
          const float var = s2[r]*(1.f/128.f) - mu*mu;
          Abuf[row*ASTR + col] =
            __float2bfloat16((xh[nt][r]-mu)*rsqrtf(var+1e-6f)*g + be);
        }
      }
    }
  }
  __syncthreads();

  // ---- fc1 GEMM (N=176) + midLN + gelu -> Abuf (A of fc2, K up to 170) ----
  {
    bf16x8 af[4];
    #pragma unroll
    for(int s = 0; s < 4; s++) af[s] = *(const bf16x8*)&Abuf[l15*ASTR + s*32 + q4*8];
    const int NT1 = wave ? 5 : 6;           // wave0 tiles 0..5, wave1 tiles 6..10
    f32x4 acc1[6];
    #pragma unroll
    for(int nt = 0; nt < 6; nt++){ acc1[nt][0]=0.f; acc1[nt][1]=0.f; acc1[nt][2]=0.f; acc1[nt][3]=0.f; }
    for(int nt = 0; nt < NT1; nt++){
      const int tI = wave ? (6 + nt) : nt;
      const int n = tI*16 + l15;
      #pragma unroll
      for(int s = 0; s < 4; s++){
        bf16x8 bf = *(const bf16x8*)&packF1[((s*176 + n)*4 + q4)*8];
        acc1[nt] = __builtin_amdgcn_mfma_f32_16x16x32_bf16(af[s], bf, acc1[nt], 0,0,0);
      }
    }
    float s1[4], s2[4];
    #pragma unroll
    for(int r = 0; r < 4; r++){ s1[r]=0.f; s2[r]=0.f; }
    for(int nt = 0; nt < NT1; nt++){
      const int tI = wave ? (6 + nt) : nt;
      const int col = tI*16 + l15;
      const float b1 = (col < 170) ? fc1_b[col] : 0.f;
      #pragma unroll
      for(int r = 0; r < 4; r++){
        const float vv = acc1[nt][r] + b1;
        acc1[nt][r] = vv; s1[r] += vv; s2[r] += vv*vv;
      }
    }
    rowred(s1, s2, red, wave, lane);
    // zero fc2's A-pad cols 170..191 (rows 0..7) — no full-buffer zero-init anymore,
    // and NaN garbage here would poison valid rows via K-dim (NaN*0=NaN in MFMA).
    for(int z = tid; z < 176; z += 128){
      const int row = z / 22, col = 170 + (z - (z/22)*22);
      Abuf[row*ASTR + col] = __float2bfloat16(0.f);
    }
    const float kA = 0.7978845608028654f, kB = 0.044715f;
    for(int nt = 0; nt < NT1; nt++){
      const int tI = wave ? (6 + nt) : nt;
      const int col = tI*16 + l15;
      if(col < 170){
        const float g = mg[col], be = mb[col];
        #pragma unroll
        for(int r = 0; r < 4; r++){
          const int row = q4*4 + r;
          if(row < 8){
            const float mu = s1[r]*(1.f/170.f);
            const float var = s2[r]*(1.f/170.f) - mu*mu;
            const float hn = (acc1[nt][r]-mu)*rsqrtf(var+1e-6f)*g + be;
            const float gl = 0.5f*hn*(1.f + tanhf(kA*(hn + kB*hn*hn*hn)));
            Abuf[row*ASTR + col] = __float2bfloat16(gl);
          }
        }
      }
    }
  }
  __syncthreads();

  // ---- fc2 GEMM (K=192) + ls2*res -> xt ----
  {
    bf16x8 af[6];
    #pragma unroll
    for(int s = 0; s < 6; s++) af[s] = *(const bf16x8*)&Abuf[l15*ASTR + s*32 + q4*8];
    f32x4 acc[4];
    #pragma unroll
    for(int nt = 0; nt < 4; nt++){ acc[nt][0]=0.f; acc[nt][1]=0.f; acc[nt][2]=0.f; acc[nt][3]=0.f; }
    #pragma unroll
    for(int nt = 0; nt < 4; nt++){
      const int n = (wave*4+nt)*16 + l15;
      #pragma unroll
      for(int s = 0; s < 6; s++){
        bf16x8 bf = *(const bf16x8*)&packF2[((s*128 + n)*4 + q4)*8];
        acc[nt] = __builtin_amdgcn_mfma_f32_16x16x32_bf16(af[s], bf, acc[nt], 0,0,0);
      }
    }
    #pragma unroll
    for(int nt = 0; nt < 4; nt++){
      const int col = (wave*4+nt)*16 + l15;
      const float bf2 = fc2_b[col], l2 = ls2[col];
      #pragma unroll
      for(int r = 0; r < 4; r++){
        const int row = q4*4 + r;
        if(row < 8)
          xt_out[p0 + ((size_t)(row>>1)<<14) + (size_t)((row&1)<<7) + col] =
            xh[nt][r] + l2*(acc[nt][r] + bf2);
      }
    }
  }
}

// ---- K4: tiled transpose xt (B,HW,C) -> out (B,C,H,W) ----
__global__ void k_tout(const float* __restrict__ xt, float* __restrict__ out){
  __shared__ float tile[32][33];
  const int b = blockIdx.z;
  const int pb = blockIdx.x * 32;
  const int cb = blockIdx.y * 32;
  const int tx = threadIdx.x, ty = threadIdx.y;
  #pragma unroll
  for(int r = 0; r < 32; r += 8)
    tile[ty+r][tx] = xt[(size_t)((b<<14) + pb + ty + r)*128 + cb + tx];
  __syncthreads();
  #pragma unroll
  for(int r = 0; r < 32; r += 8)
    out[(size_t)(b*128 + cb + ty + r)*16384 + pb + tx] = tile[tx][ty+r];
}

extern "C" void kernel_launch(void* const* d_in, const int* in_sizes, int n_in,
                              void* d_out, int out_size, void* d_ws, size_t ws_size,
                              hipStream_t stream){
  const float* x      = (const float*)d_in[0];
  const float* qkv_w  = (const float*)d_in[1];
  const float* qkv_b  = (const float*)d_in[2];
  const float* qg     = (const float*)d_in[3];
  const float* qb     = (const float*)d_in[4];
  const float* kg     = (const float*)d_in[5];
  const float* kb     = (const float*)d_in[6];
  const float* proj_w = (const float*)d_in[7];
  const float* proj_b = (const float*)d_in[8];
  const float* n1g    = (const float*)d_in[9];
  const float* n1b    = (const float*)d_in[10];
  const float* n2g    = (const float*)d_in[11];
  const float* n2b    = (const float*)d_in[12];
  const float* ls1    = (const float*)d_in[13];
  const float* ls2    = (const float*)d_in[14];
  const float* fc1_w  = (const float*)d_in[15];
  const float* fc1_b  = (const float*)d_in[16];
  const float* mg     = (const float*)d_in[17];
  const float* mb     = (const float*)d_in[18];
  const float* fc2_w  = (const float*)d_in[19];
  const float* fc2_b  = (const float*)d_in[20];

  float* ws  = (float*)d_ws;
  float* xt  = ws;
  float* kcb = ws + 4194304;
  float* vcb = ws + 5242880;
  BF* pk     = (BF*)(ws + 6291456);
  BF* packQ  = pk;
  BF* packK  = pk + 16384;
  BF* packV  = pk + 32768;
  BF* packP  = pk + 49152;
  BF* packF1 = pk + 65536;
  BF* packF2 = pk + 88064;

  dim3 tgrid(512, 4, 2), tblk(32, 8);
  k_tin <<<tgrid, tblk, 0, stream>>>(x, xt);
  k_wt  <<<440, 256, 0, stream>>>(qkv_w, proj_w, fc1_w, fc2_w, pk);
  k_kv  <<<1024, 128, 0, stream>>>(xt, packK, packV, qkv_b, kg, kb, n1g, n1b, kcb, vcb);
  k_cell<<<4096, 128, 0, stream>>>(xt, packQ, packP, packF1, packF2,
                                   qkv_b, qg, qb, n1g, n1b, proj_b, ls1, ls2,
                                   n2g, n2b, fc1_b, mg, mb, fc2_b,
                                   kcb, vcb, xt);
  k_tout<<<tgrid, tblk, 0, stream>>>(xt, (float*)d_out);
}